// Round 1
// baseline (2131.594 us; speedup 1.0000x reference)
//
#include <hip/hip_runtime.h>

constexpr int NN = 100000;   // nodes
constexpr int EE = 1600000;  // edges
constexpr int PP = 100000;   // pos/neg samples
constexpr int DH = 128;
constexpr int DM = 512;

// ---------------- CSR build (sort edges by dst, once per launch) ----------------

__global__ void hist_kernel(const int* __restrict__ dst, int* __restrict__ deg) {
  int i = blockIdx.x * 256 + threadIdx.x;
  if (i < EE) atomicAdd(&deg[dst[i]], 1);
}

// block scans 512 elements (Hillis-Steele, double buffer), writes inclusive scan + block sum
__global__ void scan1_kernel(const int* __restrict__ deg, int* __restrict__ inc,
                             int* __restrict__ bsum) {
  __shared__ int buf[2][512];
  int base = blockIdx.x * 512;
  for (int i = threadIdx.x; i < 512; i += 256) {
    int g = base + i;
    buf[0][i] = (g < NN) ? deg[g] : 0;
  }
  __syncthreads();
  int cur = 0;
  for (int off = 1; off < 512; off <<= 1) {
    int nxt = cur ^ 1;
    for (int i = threadIdx.x; i < 512; i += 256) {
      int v = buf[cur][i];
      if (i >= off) v += buf[cur][i - off];
      buf[nxt][i] = v;
    }
    __syncthreads();
    cur = nxt;
  }
  for (int i = threadIdx.x; i < 512; i += 256) {
    int g = base + i;
    if (g < NN) inc[g] = buf[cur][i];
  }
  if (threadIdx.x == 0) bsum[blockIdx.x] = buf[cur][511];
}

// single block: exclusive scan of block sums (nb <= 256)
__global__ void scan2_kernel(int* __restrict__ bsum, int nb) {
  __shared__ int buf[2][256];
  int i = threadIdx.x;
  buf[0][i] = (i < nb) ? bsum[i] : 0;
  __syncthreads();
  int cur = 0;
  for (int off = 1; off < 256; off <<= 1) {
    int nxt = cur ^ 1;
    int v = buf[cur][i];
    if (i >= off) v += buf[cur][i - off];
    buf[nxt][i] = v;
    __syncthreads();
    cur = nxt;
  }
  if (i < nb) bsum[i] = (i == 0) ? 0 : buf[cur][i - 1];
}

__global__ void scan3_kernel(const int* __restrict__ inc, const int* __restrict__ deg,
                             const int* __restrict__ bsum,
                             int* __restrict__ row_off, int* __restrict__ cursor) {
  int i = blockIdx.x * 256 + threadIdx.x;
  if (i < NN) {
    int excl = inc[i] - deg[i] + bsum[i >> 9];
    row_off[i] = excl;
    cursor[i] = excl;
    if (i == NN - 1) row_off[NN] = excl + deg[i];  // == EE
  }
}

__global__ void scatter_kernel(const int* __restrict__ esrc, const int* __restrict__ edst,
                               int* __restrict__ cursor, int* __restrict__ csr) {
  int i = blockIdx.x * 256 + threadIdx.x;
  if (i < EE) {
    int d = edst[i];
    int p = atomicAdd(&cursor[d], 1);
    csr[p] = esrc[i];
  }
}

// ---------------- aggregation: s[dst] = h[dst] + sum_{e->dst} h[src[e]] ----------------
// 32 lanes per dst row (float4 each), 8 rows per 256-thread block.
__global__ __launch_bounds__(256) void agg_kernel(const float* __restrict__ h,
                                                  const int* __restrict__ row_off,
                                                  const int* __restrict__ csr,
                                                  float* __restrict__ s) {
  int t = blockIdx.x * 256 + threadIdx.x;
  int grp = t >> 5;
  int lane = t & 31;
  if (grp >= NN) return;
  const float4* hp = (const float4*)h;
  float4 acc = hp[(size_t)grp * 32 + lane];
  int e = row_off[grp];
  int e1 = row_off[grp + 1];
  for (; e + 1 < e1; e += 2) {  // 2-wide unroll: two gathers in flight
    int s0 = csr[e];
    int s1 = csr[e + 1];
    float4 v0 = hp[(size_t)s0 * 32 + lane];
    float4 v1 = hp[(size_t)s1 * 32 + lane];
    acc.x += v0.x + v1.x;
    acc.y += v0.y + v1.y;
    acc.z += v0.z + v1.z;
    acc.w += v0.w + v1.w;
  }
  if (e < e1) {
    int s0 = csr[e];
    float4 v0 = hp[(size_t)s0 * 32 + lane];
    acc.x += v0.x; acc.y += v0.y; acc.z += v0.z; acc.w += v0.w;
  }
  ((float4*)s)[(size_t)grp * 32 + lane] = acc;
}

// ---------------- fused MLP: h = relu(relu(s@W1+b1)@W2+b2) ----------------
// 64 rows/block, 256 threads. D_MLP processed in 8 chunks of 64; z chunk staged in LDS.
// LDS strides padded (132 / 68) so the 4 distinct row addresses per read land in
// distinct banks (broadcast within 16-lane groups is free).
__global__ __launch_bounds__(256) void mlp_kernel(const float* __restrict__ s,
                                                  const float* __restrict__ W1s,
                                                  const float* __restrict__ b1s,
                                                  const float* __restrict__ W2s,
                                                  const float* __restrict__ b2s,
                                                  float* __restrict__ hout) {
  __shared__ float s_tile[64 * 132];
  __shared__ float z_tile[64 * 68];
  const int tid = threadIdx.x;
  const int row0 = blockIdx.x * 64;

  // stage s tile: 8 float4 per thread, coalesced
  #pragma unroll
  for (int i = 0; i < 8; ++i) {
    int idx = tid + i * 256;
    int r = idx >> 5;
    int c4 = (idx & 31) << 2;
    int gr = row0 + r;
    float4 v = make_float4(0.f, 0.f, 0.f, 0.f);
    if (gr < NN) v = *(const float4*)(s + (size_t)gr * DH + c4);
    *(float4*)(&s_tile[r * 132 + c4]) = v;
  }
  __syncthreads();

  const int tr = (tid >> 4) << 2;   // row micro-tile base: 0..60
  const int tc = (tid & 15) << 2;   // stage-A col base within 64-chunk
  const int tcB = (tid & 15) << 3;  // stage-B col base within 128

  float hacc[4][8];
  #pragma unroll
  for (int r = 0; r < 4; ++r)
    #pragma unroll
    for (int c = 0; c < 8; ++c) hacc[r][c] = 0.f;

  for (int ch = 0; ch < 8; ++ch) {
    // ---- stage A: z[64][64] = relu(s_tile @ W1[:, ch*64:ch*64+64] + b1) ----
    float z[4][4];
    #pragma unroll
    for (int r = 0; r < 4; ++r)
      #pragma unroll
      for (int c = 0; c < 4; ++c) z[r][c] = 0.f;

    const float* w1p = W1s + ch * 64 + tc;
    for (int k = 0; k < DH; ++k) {
      float4 w = *(const float4*)(w1p + ((size_t)k << 9));  // k*512
      float a[4];
      #pragma unroll
      for (int r = 0; r < 4; ++r) a[r] = s_tile[(tr + r) * 132 + k];
      #pragma unroll
      for (int r = 0; r < 4; ++r) {
        z[r][0] = fmaf(a[r], w.x, z[r][0]);
        z[r][1] = fmaf(a[r], w.y, z[r][1]);
        z[r][2] = fmaf(a[r], w.z, z[r][2]);
        z[r][3] = fmaf(a[r], w.w, z[r][3]);
      }
    }
    float4 bb = *(const float4*)(b1s + ch * 64 + tc);
    __syncthreads();  // prev chunk's stage B done reading z_tile
    #pragma unroll
    for (int r = 0; r < 4; ++r) {
      float4 zr;
      zr.x = fmaxf(z[r][0] + bb.x, 0.f);
      zr.y = fmaxf(z[r][1] + bb.y, 0.f);
      zr.z = fmaxf(z[r][2] + bb.z, 0.f);
      zr.w = fmaxf(z[r][3] + bb.w, 0.f);
      *(float4*)(&z_tile[(tr + r) * 68 + tc]) = zr;
    }
    __syncthreads();

    // ---- stage B: hacc[64][128] += z_tile @ W2[ch*64:ch*64+64, :] ----
    const float* w2p = W2s + (size_t)(ch * 64) * DH + tcB;
    for (int k = 0; k < 64; ++k) {
      float4 wlo = *(const float4*)(w2p + ((size_t)k << 7));
      float4 whi = *(const float4*)(w2p + ((size_t)k << 7) + 4);
      float a[4];
      #pragma unroll
      for (int r = 0; r < 4; ++r) a[r] = z_tile[(tr + r) * 68 + k];
      #pragma unroll
      for (int r = 0; r < 4; ++r) {
        hacc[r][0] = fmaf(a[r], wlo.x, hacc[r][0]);
        hacc[r][1] = fmaf(a[r], wlo.y, hacc[r][1]);
        hacc[r][2] = fmaf(a[r], wlo.z, hacc[r][2]);
        hacc[r][3] = fmaf(a[r], wlo.w, hacc[r][3]);
        hacc[r][4] = fmaf(a[r], whi.x, hacc[r][4]);
        hacc[r][5] = fmaf(a[r], whi.y, hacc[r][5]);
        hacc[r][6] = fmaf(a[r], whi.z, hacc[r][6]);
        hacc[r][7] = fmaf(a[r], whi.w, hacc[r][7]);
      }
    }
    // barrier before next chunk's z_tile write is the sync at top of stage A
  }

  // epilogue: h = relu(hacc + b2)
  float4 blo = *(const float4*)(b2s + tcB);
  float4 bhi = *(const float4*)(b2s + tcB + 4);
  #pragma unroll
  for (int r = 0; r < 4; ++r) {
    int gr = row0 + tr + r;
    if (gr < NN) {
      float4 o0, o1;
      o0.x = fmaxf(hacc[r][0] + blo.x, 0.f);
      o0.y = fmaxf(hacc[r][1] + blo.y, 0.f);
      o0.z = fmaxf(hacc[r][2] + blo.z, 0.f);
      o0.w = fmaxf(hacc[r][3] + blo.w, 0.f);
      o1.x = fmaxf(hacc[r][4] + bhi.x, 0.f);
      o1.y = fmaxf(hacc[r][5] + bhi.y, 0.f);
      o1.z = fmaxf(hacc[r][6] + bhi.z, 0.f);
      o1.w = fmaxf(hacc[r][7] + bhi.w, 0.f);
      *(float4*)(hout + (size_t)gr * DH + tcB) = o0;
      *(float4*)(hout + (size_t)gr * DH + tcB + 4) = o1;
    }
  }
}

// ---------------- link predictor: out = relu((h[s]*h[d])@Wp1+bp1)@Wp2+bp2 ----------------
// 64 samples/block (pos samples are [0,P), neg are [P,2P)); g staged in LDS,
// Wp1 read through L1 with full block reuse.
__global__ __launch_bounds__(256) void predict_kernel(
    const float* __restrict__ h, const int* __restrict__ psrc, const int* __restrict__ pdst,
    const int* __restrict__ nsrc, const int* __restrict__ ndst,
    const float* __restrict__ Wp1, const float* __restrict__ bp1,
    const float* __restrict__ Wp2, const float* __restrict__ bp2,
    float* __restrict__ out) {
  __shared__ float g_tile[64 * 132];
  const int tid = threadIdx.x;
  const int s0 = blockIdx.x * 64;

  #pragma unroll
  for (int i = 0; i < 8; ++i) {
    int idx = tid + i * 256;
    int smp = s0 + (idx >> 5);
    int c4 = (idx & 31) << 2;
    float4 g = make_float4(0.f, 0.f, 0.f, 0.f);
    if (smp < 2 * PP) {
      int si = (smp < PP) ? psrc[smp] : nsrc[smp - PP];
      int di = (smp < PP) ? pdst[smp] : ndst[smp - PP];
      float4 a = *(const float4*)(h + (size_t)si * DH + c4);
      float4 b = *(const float4*)(h + (size_t)di * DH + c4);
      g = make_float4(a.x * b.x, a.y * b.y, a.z * b.z, a.w * b.w);
    }
    *(float4*)(&g_tile[(idx >> 5) * 132 + c4]) = g;
  }
  __syncthreads();

  const int tr = (tid >> 4) << 2;  // 4 samples per thread
  const int tc = (tid & 15) << 2;  // 4 of 64 pred cols
  float z[4][4];
  #pragma unroll
  for (int r = 0; r < 4; ++r)
    #pragma unroll
    for (int c = 0; c < 4; ++c) z[r][c] = 0.f;

  for (int k = 0; k < DH; ++k) {
    float4 w = *(const float4*)(Wp1 + ((size_t)k << 6) + tc);
    float a[4];
    #pragma unroll
    for (int r = 0; r < 4; ++r) a[r] = g_tile[(tr + r) * 132 + k];
    #pragma unroll
    for (int r = 0; r < 4; ++r) {
      z[r][0] = fmaf(a[r], w.x, z[r][0]);
      z[r][1] = fmaf(a[r], w.y, z[r][1]);
      z[r][2] = fmaf(a[r], w.z, z[r][2]);
      z[r][3] = fmaf(a[r], w.w, z[r][3]);
    }
  }

  float4 b1v = *(const float4*)(bp1 + tc);
  float4 w2v = *(const float4*)(Wp2 + tc);
  float part[4];
  #pragma unroll
  for (int r = 0; r < 4; ++r) {
    part[r] = fmaxf(z[r][0] + b1v.x, 0.f) * w2v.x +
              fmaxf(z[r][1] + b1v.y, 0.f) * w2v.y +
              fmaxf(z[r][2] + b1v.z, 0.f) * w2v.z +
              fmaxf(z[r][3] + b1v.w, 0.f) * w2v.w;
  }
  // reduce across the 16 col-groups (contiguous 16-lane groups within the wave)
  #pragma unroll
  for (int off = 1; off < 16; off <<= 1) {
    #pragma unroll
    for (int r = 0; r < 4; ++r) part[r] += __shfl_xor(part[r], off, 64);
  }
  if ((tid & 15) == 0) {
    float bias = bp2[0];
    #pragma unroll
    for (int r = 0; r < 4; ++r) {
      int smp = s0 + tr + r;
      if (smp < 2 * PP) out[smp] = part[r] + bias;
    }
  }
}

// ---------------- launcher ----------------
extern "C" void kernel_launch(void* const* d_in, const int* in_sizes, int n_in,
                              void* d_out, int out_size, void* d_ws, size_t ws_size,
                              hipStream_t stream) {
  const float* x   = (const float*)d_in[0];
  const float* W1  = (const float*)d_in[1];
  const float* b1  = (const float*)d_in[2];
  const float* W2  = (const float*)d_in[3];
  const float* b2  = (const float*)d_in[4];
  const float* Wp1 = (const float*)d_in[5];
  const float* bp1 = (const float*)d_in[6];
  const float* Wp2 = (const float*)d_in[7];
  const float* bp2 = (const float*)d_in[8];
  const int* esrc = (const int*)d_in[9];
  const int* edst = (const int*)d_in[10];
  const int* psrc = (const int*)d_in[11];
  const int* pdst = (const int*)d_in[12];
  const int* nsrc = (const int*)d_in[13];
  const int* ndst = (const int*)d_in[14];

  float* out = (float*)d_out;
  float* out_pred = out;              // [2P]: h_pos then h_neg (contiguous)
  float* hbuf = out + 2 * (size_t)PP; // [N,128] final h lives here; also ping buffer

  // workspace layout (~59 MB)
  char* w = (char*)d_ws;
  float* s_buf = (float*)w;                              // N*128 f32 = 51.2 MB
  int* deg     = (int*)(w + (size_t)NN * DH * 4);        // N
  int* inc     = deg + NN;                               // N
  int* bsum    = inc + NN;                               // 256
  int* row_off = bsum + 256;                             // N+1
  int* cursor  = row_off + (NN + 1);                     // N
  int* csr     = cursor + NN;                            // E

  // ---- CSR build (per launch; ws is re-poisoned every call) ----
  hipMemsetAsync(deg, 0, NN * sizeof(int), stream);
  hist_kernel<<<(EE + 255) / 256, 256, 0, stream>>>(edst, deg);
  scan1_kernel<<<(NN + 511) / 512, 256, 0, stream>>>(deg, inc, bsum);
  scan2_kernel<<<1, 256, 0, stream>>>(bsum, (NN + 511) / 512);
  scan3_kernel<<<(NN + 255) / 256, 256, 0, stream>>>(inc, deg, bsum, row_off, cursor);
  scatter_kernel<<<(EE + 255) / 256, 256, 0, stream>>>(esrc, edst, cursor, csr);

  // ---- 3 GIN layers: agg(h -> s), mlp(s -> h). h lives in out's h region. ----
  const float* hcur = x;
  for (int l = 0; l < 3; ++l) {
    agg_kernel<<<(NN * 32 + 255) / 256, 256, 0, stream>>>(hcur, row_off, csr, s_buf);
    mlp_kernel<<<(NN + 63) / 64, 256, 0, stream>>>(
        s_buf, W1 + (size_t)l * DH * DM, b1 + (size_t)l * DM,
        W2 + (size_t)l * DM * DH, b2 + (size_t)l * DH, hbuf);
    hcur = hbuf;
  }

  // ---- link prediction for pos + neg in one grid ----
  predict_kernel<<<(2 * PP + 63) / 64, 256, 0, stream>>>(
      hbuf, psrc, pdst, nsrc, ndst, Wp1, bp1, Wp2, bp2, out_pred);
}

// Round 3
// 1164.539 us; speedup vs baseline: 1.8304x; 1.8304x over previous
//
#include <hip/hip_runtime.h>

typedef unsigned short ushort_t;

constexpr int NN = 100000;   // nodes
constexpr int EE = 1600000;  // edges
constexpr int PP = 100000;   // pos/neg samples
constexpr int DH = 128;
constexpr int DM = 512;

using frag_b16 = __attribute__((ext_vector_type(8))) short;   // 8 bf16 (4 VGPRs)
using frag_f32 = __attribute__((ext_vector_type(4))) float;   // 4 fp32 acc

union FragU {
  ushort_t s[8];
  uint4 u;
  frag_b16 f;
};

// split fp32 into bf16 hi (truncate) + bf16 lo (RNE of residual): x ~= hi+lo, err ~2^-17|x|
__device__ inline void split_bf16(float x, ushort_t& hi, ushort_t& lo) {
  unsigned int bx = __float_as_uint(x);
  hi = (ushort_t)(bx >> 16);
  float hf = __uint_as_float(bx & 0xFFFF0000u);
  float r = x - hf;
  unsigned int br = __float_as_uint(r);
  unsigned int rb = br + 0x7FFFu + ((br >> 16) & 1u);  // RNE
  lo = (ushort_t)(rb >> 16);
}

// ---------------- CSR build (sort edges by dst, once per launch) ----------------

__global__ void hist_kernel(const int* __restrict__ dst, int* __restrict__ deg) {
  int i = blockIdx.x * 256 + threadIdx.x;
  if (i < EE) atomicAdd(&deg[dst[i]], 1);
}

__global__ void scan1_kernel(const int* __restrict__ deg, int* __restrict__ inc,
                             int* __restrict__ bsum) {
  __shared__ int buf[2][512];
  int base = blockIdx.x * 512;
  for (int i = threadIdx.x; i < 512; i += 256) {
    int g = base + i;
    buf[0][i] = (g < NN) ? deg[g] : 0;
  }
  __syncthreads();
  int cur = 0;
  for (int off = 1; off < 512; off <<= 1) {
    int nxt = cur ^ 1;
    for (int i = threadIdx.x; i < 512; i += 256) {
      int v = buf[cur][i];
      if (i >= off) v += buf[cur][i - off];
      buf[nxt][i] = v;
    }
    __syncthreads();
    cur = nxt;
  }
  for (int i = threadIdx.x; i < 512; i += 256) {
    int g = base + i;
    if (g < NN) inc[g] = buf[cur][i];
  }
  if (threadIdx.x == 0) bsum[blockIdx.x] = buf[cur][511];
}

__global__ void scan2_kernel(int* __restrict__ bsum, int nb) {
  __shared__ int buf[2][256];
  int i = threadIdx.x;
  buf[0][i] = (i < nb) ? bsum[i] : 0;
  __syncthreads();
  int cur = 0;
  for (int off = 1; off < 256; off <<= 1) {
    int nxt = cur ^ 1;
    int v = buf[cur][i];
    if (i >= off) v += buf[cur][i - off];
    buf[nxt][i] = v;
    __syncthreads();
    cur = nxt;
  }
  if (i < nb) bsum[i] = (i == 0) ? 0 : buf[cur][i - 1];
}

__global__ void scan3_kernel(const int* __restrict__ inc, const int* __restrict__ deg,
                             const int* __restrict__ bsum,
                             int* __restrict__ row_off, int* __restrict__ cursor) {
  int i = blockIdx.x * 256 + threadIdx.x;
  if (i < NN) {
    int excl = inc[i] - deg[i] + bsum[i >> 9];
    row_off[i] = excl;
    cursor[i] = excl;
    if (i == NN - 1) row_off[NN] = excl + deg[i];
  }
}

__global__ void scatter_kernel(const int* __restrict__ esrc, const int* __restrict__ edst,
                               int* __restrict__ cursor, int* __restrict__ csr) {
  int i = blockIdx.x * 256 + threadIdx.x;
  if (i < EE) {
    int d = edst[i];
    int p = atomicAdd(&cursor[d], 1);
    csr[p] = esrc[i];
  }
}

// ---------------- weight packing into MFMA B-fragment order, bf16 hi/lo ----------------
// W1 [L][128(K)][512(N)] -> per layer, tiles tn(32) x tk(4), lane 64, j 8:
//   flat = ((layer*128 + tn*4 + tk)*64 + lane)*8,  n = tn*16+(lane&15), k = tk*32+(lane>>4)*8+j
__global__ void pack_w1_kernel(const float* __restrict__ W1,
                               ushort_t* __restrict__ wh, ushort_t* __restrict__ wl) {
  int t = blockIdx.x * 256 + threadIdx.x;
  if (t >= 3 * 128 * 64) return;
  int lane = t & 63;
  int tile = t >> 6;
  int tk = tile & 3;
  int tn = (tile >> 2) & 31;
  int layer = tile >> 7;
  int n = tn * 16 + (lane & 15);
  int k0 = tk * 32 + (lane >> 4) * 8;
  const float* src = W1 + (size_t)layer * DH * DM;
  size_t dst = (size_t)t * 8;
  #pragma unroll
  for (int j = 0; j < 8; ++j) {
    ushort_t hi, lo;
    split_bf16(src[(size_t)(k0 + j) * DM + n], hi, lo);
    wh[dst + j] = hi;
    wl[dst + j] = lo;
  }
}

// W2 [L][512(K)][128(N)] -> tiles tn(8) x tk(16): flat = ((layer*128 + tn*16 + tk)*64 + lane)*8
__global__ void pack_w2_kernel(const float* __restrict__ W2,
                               ushort_t* __restrict__ wh, ushort_t* __restrict__ wl) {
  int t = blockIdx.x * 256 + threadIdx.x;
  if (t >= 3 * 128 * 64) return;
  int lane = t & 63;
  int tile = t >> 6;
  int tk = tile & 15;
  int tn = (tile >> 4) & 7;
  int layer = tile >> 7;
  int n = tn * 16 + (lane & 15);
  int k0 = tk * 32 + (lane >> 4) * 8;
  const float* src = W2 + (size_t)layer * DM * DH;
  size_t dst = (size_t)t * 8;
  #pragma unroll
  for (int j = 0; j < 8; ++j) {
    ushort_t hi, lo;
    split_bf16(src[(size_t)(k0 + j) * DH + n], hi, lo);
    wh[dst + j] = hi;
    wl[dst + j] = lo;
  }
}

// ---------------- aggregation: s[dst] = h[dst] + sum h[src];  emit bf16 hi/lo planes ------
__global__ __launch_bounds__(256) void agg_kernel(const float* __restrict__ h,
                                                  const int* __restrict__ row_off,
                                                  const int* __restrict__ csr,
                                                  ushort_t* __restrict__ s_hi,
                                                  ushort_t* __restrict__ s_lo) {
  int t = blockIdx.x * 256 + threadIdx.x;
  int grp = t >> 5;
  int lane = t & 31;
  if (grp >= NN) return;
  const float4* hp = (const float4*)h;
  float4 acc = hp[(size_t)grp * 32 + lane];
  int e = row_off[grp];
  int e1 = row_off[grp + 1];
  for (; e + 1 < e1; e += 2) {
    int s0 = csr[e];
    int s1 = csr[e + 1];
    float4 v0 = hp[(size_t)s0 * 32 + lane];
    float4 v1 = hp[(size_t)s1 * 32 + lane];
    acc.x += v0.x + v1.x;
    acc.y += v0.y + v1.y;
    acc.z += v0.z + v1.z;
    acc.w += v0.w + v1.w;
  }
  if (e < e1) {
    int s0 = csr[e];
    float4 v0 = hp[(size_t)s0 * 32 + lane];
    acc.x += v0.x; acc.y += v0.y; acc.z += v0.z; acc.w += v0.w;
  }
  ushort4 h4, l4;
  split_bf16(acc.x, h4.x, l4.x);
  split_bf16(acc.y, h4.y, l4.y);
  split_bf16(acc.z, h4.z, l4.z);
  split_bf16(acc.w, h4.w, l4.w);
  size_t o = (size_t)grp * DH + lane * 4;
  *(ushort4*)(s_hi + o) = h4;
  *(ushort4*)(s_lo + o) = l4;
}

// ---------------- fused MFMA MLP: h = relu(relu(s@W1+b1)@W2+b2) ----------------
// 64 rows/block (wave w owns rows 16w..16w+15). Split-precision bf16: 3 MFMA passes.
// z transposed through wave-private LDS slice -> NO __syncthreads anywhere.
__global__ __launch_bounds__(256) void mlp_kernel(
    const ushort_t* __restrict__ s_hi, const ushort_t* __restrict__ s_lo,
    const ushort_t* __restrict__ w1h, const ushort_t* __restrict__ w1l,
    const float* __restrict__ b1s,
    const ushort_t* __restrict__ w2h, const ushort_t* __restrict__ w2l,
    const float* __restrict__ b2s,
    float* __restrict__ hout) {
  __shared__ float zt[64 * 66];  // [k_z 0..63][m 0..63 +pad2]
  const int tid = threadIdx.x;
  const int wave = tid >> 6;
  const int lane = tid & 63;
  const int quad = lane >> 4;
  const int l15 = lane & 15;
  const int m_base = wave * 16;
  const int row0 = blockIdx.x * 64;

  // ---- A-fragments (s rows, bf16 hi/lo) held in registers for the whole kernel ----
  int gr_ld = row0 + m_base + l15;
  if (gr_ld >= NN) gr_ld = NN - 1;  // clamp: stores are guarded
  frag_b16 a_hi[4], a_lo[4];
  #pragma unroll
  for (int tk = 0; tk < 4; ++tk) {
    size_t o = (size_t)gr_ld * DH + tk * 32 + quad * 8;
    FragU uh, ul;
    uh.u = *(const uint4*)(s_hi + o);
    ul.u = *(const uint4*)(s_lo + o);
    a_hi[tk] = uh.f;
    a_lo[tk] = ul.f;
  }

  frag_f32 hacc[8];
  #pragma unroll
  for (int tn = 0; tn < 8; ++tn) hacc[tn] = {0.f, 0.f, 0.f, 0.f};

  for (int ch = 0; ch < 8; ++ch) {
    // ---- stage A: z[64 rows][64 cols] = relu(s @ W1[:, ch*64..+64] + b1) ----
    frag_f32 za[4];
    #pragma unroll
    for (int tn = 0; tn < 4; ++tn) za[tn] = {0.f, 0.f, 0.f, 0.f};

    #pragma unroll
    for (int tk = 0; tk < 4; ++tk) {
      #pragma unroll
      for (int tn = 0; tn < 4; ++tn) {
        int tn_g = ch * 4 + tn;
        size_t flat = ((size_t)(tn_g * 4 + tk) * 64 + lane) * 8;
        FragU bh, bl;
        bh.u = *(const uint4*)(w1h + flat);
        bl.u = *(const uint4*)(w1l + flat);
        za[tn] = __builtin_amdgcn_mfma_f32_16x16x32_bf16(a_hi[tk], bh.f, za[tn], 0, 0, 0);
        za[tn] = __builtin_amdgcn_mfma_f32_16x16x32_bf16(a_lo[tk], bh.f, za[tn], 0, 0, 0);
        za[tn] = __builtin_amdgcn_mfma_f32_16x16x32_bf16(a_hi[tk], bl.f, za[tn], 0, 0, 0);
      }
    }

    // relu+bias, write to wave-private z_t slice (cols = all, rows = this wave's 16)
    #pragma unroll
    for (int tn = 0; tn < 4; ++tn) {
      float b1v = b1s[ch * 64 + tn * 16 + l15];
      float z0 = fmaxf(za[tn][0] + b1v, 0.f);
      float z1 = fmaxf(za[tn][1] + b1v, 0.f);
      float z2 = fmaxf(za[tn][2] + b1v, 0.f);
      float z3 = fmaxf(za[tn][3] + b1v, 0.f);
      float* zp = &zt[(tn * 16 + l15) * 66 + m_base + quad * 4];
      *(float2*)zp = make_float2(z0, z1);
      *(float2*)(zp + 2) = make_float2(z2, z3);
    }
    // no barrier: each wave reads back only its own m-slice (compiler emits lgkmcnt)

    // ---- stage B: hacc += z @ W2[ch*64..+64, :] ----
    #pragma unroll
    for (int kt = 0; kt < 2; ++kt) {
      FragU zh, zl;
      #pragma unroll
      for (int j = 0; j < 8; ++j) {
        int k = kt * 32 + quad * 8 + j;
        float v = zt[k * 66 + m_base + l15];
        split_bf16(v, zh.s[j], zl.s[j]);
      }
      int ktg = ch * 2 + kt;
      #pragma unroll
      for (int tn = 0; tn < 8; ++tn) {
        size_t flat = ((size_t)(tn * 16 + ktg) * 64 + lane) * 8;
        FragU bh, bl;
        bh.u = *(const uint4*)(w2h + flat);
        bl.u = *(const uint4*)(w2l + flat);
        hacc[tn] = __builtin_amdgcn_mfma_f32_16x16x32_bf16(zh.f, bh.f, hacc[tn], 0, 0, 0);
        hacc[tn] = __builtin_amdgcn_mfma_f32_16x16x32_bf16(zl.f, bh.f, hacc[tn], 0, 0, 0);
        hacc[tn] = __builtin_amdgcn_mfma_f32_16x16x32_bf16(zh.f, bl.f, hacc[tn], 0, 0, 0);
      }
    }
  }

  // ---- epilogue: h = relu(hacc + b2), scalar stores (16-lane groups are 64B-contiguous) ----
  #pragma unroll
  for (int tn = 0; tn < 8; ++tn) {
    int col = tn * 16 + l15;
    float b2v = b2s[col];
    #pragma unroll
    for (int r = 0; r < 4; ++r) {
      int gr = row0 + m_base + quad * 4 + r;
      if (gr < NN) hout[(size_t)gr * DH + col] = fmaxf(hacc[tn][r] + b2v, 0.f);
    }
  }
}

// ---------------- link predictor (unchanged from R1) ----------------
__global__ __launch_bounds__(256) void predict_kernel(
    const float* __restrict__ h, const int* __restrict__ psrc, const int* __restrict__ pdst,
    const int* __restrict__ nsrc, const int* __restrict__ ndst,
    const float* __restrict__ Wp1, const float* __restrict__ bp1,
    const float* __restrict__ Wp2, const float* __restrict__ bp2,
    float* __restrict__ out) {
  __shared__ float g_tile[64 * 132];
  const int tid = threadIdx.x;
  const int s0 = blockIdx.x * 64;

  #pragma unroll
  for (int i = 0; i < 8; ++i) {
    int idx = tid + i * 256;
    int smp = s0 + (idx >> 5);
    int c4 = (idx & 31) << 2;
    float4 g = make_float4(0.f, 0.f, 0.f, 0.f);
    if (smp < 2 * PP) {
      int si = (smp < PP) ? psrc[smp] : nsrc[smp - PP];
      int di = (smp < PP) ? pdst[smp] : ndst[smp - PP];
      float4 a = *(const float4*)(h + (size_t)si * DH + c4);
      float4 b = *(const float4*)(h + (size_t)di * DH + c4);
      g = make_float4(a.x * b.x, a.y * b.y, a.z * b.z, a.w * b.w);
    }
    *(float4*)(&g_tile[(idx >> 5) * 132 + c4]) = g;
  }
  __syncthreads();

  const int tr = (tid >> 4) << 2;
  const int tc = (tid & 15) << 2;
  float z[4][4];
  #pragma unroll
  for (int r = 0; r < 4; ++r)
    #pragma unroll
    for (int c = 0; c < 4; ++c) z[r][c] = 0.f;

  for (int k = 0; k < DH; ++k) {
    float4 w = *(const float4*)(Wp1 + ((size_t)k << 6) + tc);
    float a[4];
    #pragma unroll
    for (int r = 0; r < 4; ++r) a[r] = g_tile[(tr + r) * 132 + k];
    #pragma unroll
    for (int r = 0; r < 4; ++r) {
      z[r][0] = fmaf(a[r], w.x, z[r][0]);
      z[r][1] = fmaf(a[r], w.y, z[r][1]);
      z[r][2] = fmaf(a[r], w.z, z[r][2]);
      z[r][3] = fmaf(a[r], w.w, z[r][3]);
    }
  }

  float4 b1v = *(const float4*)(bp1 + tc);
  float4 w2v = *(const float4*)(Wp2 + tc);
  float part[4];
  #pragma unroll
  for (int r = 0; r < 4; ++r) {
    part[r] = fmaxf(z[r][0] + b1v.x, 0.f) * w2v.x +
              fmaxf(z[r][1] + b1v.y, 0.f) * w2v.y +
              fmaxf(z[r][2] + b1v.z, 0.f) * w2v.z +
              fmaxf(z[r][3] + b1v.w, 0.f) * w2v.w;
  }
  #pragma unroll
  for (int off = 1; off < 16; off <<= 1) {
    #pragma unroll
    for (int r = 0; r < 4; ++r) part[r] += __shfl_xor(part[r], off, 64);
  }
  if ((tid & 15) == 0) {
    float bias = bp2[0];
    #pragma unroll
    for (int r = 0; r < 4; ++r) {
      int smp = s0 + tr + r;
      if (smp < 2 * PP) out[smp] = part[r] + bias;
    }
  }
}

// ---------------- launcher ----------------
extern "C" void kernel_launch(void* const* d_in, const int* in_sizes, int n_in,
                              void* d_out, int out_size, void* d_ws, size_t ws_size,
                              hipStream_t stream) {
  const float* x   = (const float*)d_in[0];
  const float* W1  = (const float*)d_in[1];
  const float* b1  = (const float*)d_in[2];
  const float* W2  = (const float*)d_in[3];
  const float* b2  = (const float*)d_in[4];
  const float* Wp1 = (const float*)d_in[5];
  const float* bp1 = (const float*)d_in[6];
  const float* Wp2 = (const float*)d_in[7];
  const float* bp2 = (const float*)d_in[8];
  const int* esrc = (const int*)d_in[9];
  const int* edst = (const int*)d_in[10];
  const int* psrc = (const int*)d_in[11];
  const int* pdst = (const int*)d_in[12];
  const int* nsrc = (const int*)d_in[13];
  const int* ndst = (const int*)d_in[14];

  float* out = (float*)d_out;
  float* out_pred = out;               // [2P]
  float* hbuf = out + 2 * (size_t)PP;  // [N,128] fp32 h

  // ---- workspace layout (~59.6 MB) ----
  char* w = (char*)d_ws;
  ushort_t* s_hi = (ushort_t*)w;                       // N*128 bf16 = 25.6 MB
  ushort_t* s_lo = s_hi + (size_t)NN * DH;             // 25.6 MB
  // packed weights directly after s planes (16B-aligned)
  ushort_t* w1h = (ushort_t*)(w + 2 * (size_t)NN * DH * sizeof(ushort_t));
  ushort_t* w1l = w1h + 3 * 128 * 64 * 8;              // 393 KB each plane
  ushort_t* w2h = w1l + 3 * 128 * 64 * 8;
  ushort_t* w2l = w2h + 3 * 128 * 64 * 8;
  int* row_off = (int*)(w2l + 3 * 128 * 64 * 8);       // N+1
  int* csr     = row_off + (NN + 1);                   // E (6.4 MB)
  // CSR-build scratch aliases the (not-yet-written) s_hi region:
  int* deg    = (int*)w;
  int* inc    = deg + NN;
  int* bsum   = inc + NN;
  int* cursor = bsum + 256;

  // ---- CSR build ----
  hipMemsetAsync(deg, 0, NN * sizeof(int), stream);
  hist_kernel<<<(EE + 255) / 256, 256, 0, stream>>>(edst, deg);
  scan1_kernel<<<(NN + 511) / 512, 256, 0, stream>>>(deg, inc, bsum);
  scan2_kernel<<<1, 256, 0, stream>>>(bsum, (NN + 511) / 512);
  scan3_kernel<<<(NN + 255) / 256, 256, 0, stream>>>(inc, deg, bsum, row_off, cursor);
  scatter_kernel<<<(EE + 255) / 256, 256, 0, stream>>>(esrc, edst, cursor, csr);

  // ---- pack weights (bf16 hi/lo, MFMA fragment order) ----
  pack_w1_kernel<<<96, 256, 0, stream>>>(W1, w1h, w1l);
  pack_w2_kernel<<<96, 256, 0, stream>>>(W2, w2h, w2l);

  // ---- 3 GIN layers ----
  const float* hcur = x;
  for (int l = 0; l < 3; ++l) {
    agg_kernel<<<(NN * 32 + 255) / 256, 256, 0, stream>>>(hcur, row_off, csr, s_hi, s_lo);
    mlp_kernel<<<(NN + 63) / 64, 256, 0, stream>>>(
        s_hi, s_lo,
        w1h + (size_t)l * 128 * 64 * 8, w1l + (size_t)l * 128 * 64 * 8, b1 + (size_t)l * DM,
        w2h + (size_t)l * 128 * 64 * 8, w2l + (size_t)l * 128 * 64 * 8, b2 + (size_t)l * DH,
        hbuf);
    hcur = hbuf;
  }

  // ---- link prediction ----
  predict_kernel<<<(2 * PP + 63) / 64, 256, 0, stream>>>(
      hbuf, psrc, pdst, nsrc, ndst, Wp1, bp1, Wp2, bp2, out_pred);
}

// Round 6
// 1086.050 us; speedup vs baseline: 1.9627x; 1.0723x over previous
//
#include <hip/hip_runtime.h>

typedef unsigned short ushort_t;

constexpr int NN = 100000;   // nodes
constexpr int EE = 1600000;  // edges
constexpr int PP = 100000;   // pos/neg samples
constexpr int DH = 128;
constexpr int DM = 512;

using frag_b16 = __attribute__((ext_vector_type(8))) short;   // 8 bf16 (4 VGPRs)
using frag_f32 = __attribute__((ext_vector_type(4))) float;   // 4 fp32 acc

union FragU {
  ushort_t s[8];
  uint4 u;
  frag_b16 f;
};

// split fp32 into bf16 hi (truncate) + bf16 lo (RNE of residual): x ~= hi+lo, err ~2^-17|x|
__device__ inline void split_bf16(float x, ushort_t& hi, ushort_t& lo) {
  unsigned int bx = __float_as_uint(x);
  hi = (ushort_t)(bx >> 16);
  float hf = __uint_as_float(bx & 0xFFFF0000u);
  float r = x - hf;
  unsigned int br = __float_as_uint(r);
  unsigned int rb = br + 0x7FFFu + ((br >> 16) & 1u);  // RNE
  lo = (ushort_t)(rb >> 16);
}

__device__ inline ushort_t rne_bf16(float x) {
  unsigned int u = __float_as_uint(x);
  unsigned int r = u + 0x7FFFu + ((u >> 16) & 1u);
  return (ushort_t)(r >> 16);
}

// unpack 2 bf16 from packed uint: low half -> a (even col), high half -> b (odd col)
__device__ inline void bf2x(unsigned int u, float& a, float& b) {
  a = __uint_as_float(u << 16);
  b = __uint_as_float(u & 0xFFFF0000u);
}

// plain-function weight fetchers (no lambdas)
__device__ inline void ldw_rec(const ushort_t* __restrict__ wp, int tile, int lane,
                               FragU& h, FragU& l) {
  const uint4* p = (const uint4*)(wp + ((size_t)(tile * 64 + lane)) * 16);
  h.u = p[0];
  l.u = p[1];
}

// ---------------- CSR build (sort edges by dst, once per launch) ----------------

__global__ void hist_kernel(const int* __restrict__ dst, int* __restrict__ deg) {
  int i = blockIdx.x * 256 + threadIdx.x;
  if (i < EE) atomicAdd(&deg[dst[i]], 1);
}

__global__ void scan1_kernel(const int* __restrict__ deg, int* __restrict__ inc,
                             int* __restrict__ bsum) {
  __shared__ int buf[2][512];
  int base = blockIdx.x * 512;
  for (int i = threadIdx.x; i < 512; i += 256) {
    int g = base + i;
    buf[0][i] = (g < NN) ? deg[g] : 0;
  }
  __syncthreads();
  int cur = 0;
  for (int off = 1; off < 512; off <<= 1) {
    int nxt = cur ^ 1;
    for (int i = threadIdx.x; i < 512; i += 256) {
      int v = buf[cur][i];
      if (i >= off) v += buf[cur][i - off];
      buf[nxt][i] = v;
    }
    __syncthreads();
    cur = nxt;
  }
  for (int i = threadIdx.x; i < 512; i += 256) {
    int g = base + i;
    if (g < NN) inc[g] = buf[cur][i];
  }
  if (threadIdx.x == 0) bsum[blockIdx.x] = buf[cur][511];
}

__global__ void scan2_kernel(int* __restrict__ bsum, int nb) {
  __shared__ int buf[2][256];
  int i = threadIdx.x;
  buf[0][i] = (i < nb) ? bsum[i] : 0;
  __syncthreads();
  int cur = 0;
  for (int off = 1; off < 256; off <<= 1) {
    int nxt = cur ^ 1;
    int v = buf[cur][i];
    if (i >= off) v += buf[cur][i - off];
    buf[nxt][i] = v;
    __syncthreads();
    cur = nxt;
  }
  if (i < nb) bsum[i] = (i == 0) ? 0 : buf[cur][i - 1];
}

__global__ void scan3_kernel(const int* __restrict__ inc, const int* __restrict__ deg,
                             const int* __restrict__ bsum,
                             int* __restrict__ row_off, int* __restrict__ cursor) {
  int i = blockIdx.x * 256 + threadIdx.x;
  if (i < NN) {
    int excl = inc[i] - deg[i] + bsum[i >> 9];
    row_off[i] = excl;
    cursor[i] = excl;
    if (i == NN - 1) row_off[NN] = excl + deg[i];
  }
}

__global__ void scatter_kernel(const int* __restrict__ esrc, const int* __restrict__ edst,
                               int* __restrict__ cursor, int* __restrict__ csr) {
  int i = blockIdx.x * 256 + threadIdx.x;
  if (i < EE) {
    int d = edst[i];
    int p = atomicAdd(&cursor[d], 1);
    csr[p] = esrc[i];
  }
}

// ---------------- weight packing: MFMA B-frag order, hi/lo interleaved 32B records ----
// record r = tile_global*64+lane holds [8 hi bf16][8 lo bf16] at wp + r*16 (ushorts).
// W1 [L][128(K)][512(N)]: tile = tn*4+tk (tn<32,tk<4), n=tn*16+(lane&15), k=tk*32+(lane>>4)*8+j
__global__ void pack_w1_kernel(const float* __restrict__ W1, ushort_t* __restrict__ wp) {
  int t = blockIdx.x * 256 + threadIdx.x;
  if (t >= 3 * 128 * 64) return;
  int lane = t & 63;
  int tile = t >> 6;
  int tk = tile & 3;
  int tn = (tile >> 2) & 31;
  int layer = tile >> 7;
  int n = tn * 16 + (lane & 15);
  int k0 = tk * 32 + (lane >> 4) * 8;
  const float* src = W1 + (size_t)layer * DH * DM;
  size_t dst = (size_t)t * 16;
  #pragma unroll
  for (int j = 0; j < 8; ++j) {
    ushort_t hi, lo;
    split_bf16(src[(size_t)(k0 + j) * DM + n], hi, lo);
    wp[dst + j] = hi;
    wp[dst + 8 + j] = lo;
  }
}

// W2 [L][512(K)][128(N)]: tile = tn*16+tk (tn<8, tk<16)
__global__ void pack_w2_kernel(const float* __restrict__ W2, ushort_t* __restrict__ wp) {
  int t = blockIdx.x * 256 + threadIdx.x;
  if (t >= 3 * 128 * 64) return;
  int lane = t & 63;
  int tile = t >> 6;
  int tk = tile & 15;
  int tn = (tile >> 4) & 7;
  int layer = tile >> 7;
  int n = tn * 16 + (lane & 15);
  int k0 = tk * 32 + (lane >> 4) * 8;
  const float* src = W2 + (size_t)layer * DM * DH;
  size_t dst = (size_t)t * 16;
  #pragma unroll
  for (int j = 0; j < 8; ++j) {
    ushort_t hi, lo;
    split_bf16(src[(size_t)(k0 + j) * DH + n], hi, lo);
    wp[dst + j] = hi;
    wp[dst + 8 + j] = lo;
  }
}

// ---------------- x -> bf16 convert (layer-0 gather source) ----------------
__global__ void cvt_bf16_kernel(const float* __restrict__ x, ushort_t* __restrict__ xb) {
  int i = blockIdx.x * 256 + threadIdx.x;  // n = NN*DH/4 quads
  if (i < NN * DH / 4) {
    float4 v = ((const float4*)x)[i];
    ushort4 o;
    o.x = rne_bf16(v.x); o.y = rne_bf16(v.y); o.z = rne_bf16(v.z); o.w = rne_bf16(v.w);
    ((ushort4*)xb)[i] = o;
  }
}

// ---------------- aggregation: s[dst] = h[dst] + sum h[src] over bf16 h ----------------
// 16 lanes/row, 16 B (8 bf16 cols) per lane; 16 rows per 256-thread block.
__global__ __launch_bounds__(256) void agg_kernel(const ushort_t* __restrict__ hbf,
                                                  const int* __restrict__ row_off,
                                                  const int* __restrict__ csr,
                                                  ushort_t* __restrict__ s_hi,
                                                  ushort_t* __restrict__ s_lo) {
  int t = blockIdx.x * 256 + threadIdx.x;
  int grp = t >> 4;
  int lane = t & 15;
  if (grp >= NN) return;
  const uint4* hp = (const uint4*)hbf;  // 16 uint4 per 128-col row
  float acc[8];
  {
    uint4 v = hp[(size_t)grp * 16 + lane];
    bf2x(v.x, acc[0], acc[1]);
    bf2x(v.y, acc[2], acc[3]);
    bf2x(v.z, acc[4], acc[5]);
    bf2x(v.w, acc[6], acc[7]);
  }
  int e = row_off[grp];
  int e1 = row_off[grp + 1];
  for (; e + 1 < e1; e += 2) {  // two gathers in flight
    uint4 a = hp[(size_t)csr[e] * 16 + lane];
    uint4 b = hp[(size_t)csr[e + 1] * 16 + lane];
    float f0, f1;
    bf2x(a.x, f0, f1); acc[0] += f0; acc[1] += f1;
    bf2x(a.y, f0, f1); acc[2] += f0; acc[3] += f1;
    bf2x(a.z, f0, f1); acc[4] += f0; acc[5] += f1;
    bf2x(a.w, f0, f1); acc[6] += f0; acc[7] += f1;
    bf2x(b.x, f0, f1); acc[0] += f0; acc[1] += f1;
    bf2x(b.y, f0, f1); acc[2] += f0; acc[3] += f1;
    bf2x(b.z, f0, f1); acc[4] += f0; acc[5] += f1;
    bf2x(b.w, f0, f1); acc[6] += f0; acc[7] += f1;
  }
  if (e < e1) {
    uint4 a = hp[(size_t)csr[e] * 16 + lane];
    float f0, f1;
    bf2x(a.x, f0, f1); acc[0] += f0; acc[1] += f1;
    bf2x(a.y, f0, f1); acc[2] += f0; acc[3] += f1;
    bf2x(a.z, f0, f1); acc[4] += f0; acc[5] += f1;
    bf2x(a.w, f0, f1); acc[6] += f0; acc[7] += f1;
  }
  // split to hi/lo planes, 16 B per lane each
  unsigned int hw[4], lw[4];
  #pragma unroll
  for (int i = 0; i < 4; ++i) {
    ushort_t h0, l0, h1, l1;
    split_bf16(acc[2 * i], h0, l0);
    split_bf16(acc[2 * i + 1], h1, l1);
    hw[i] = (unsigned int)h0 | ((unsigned int)h1 << 16);
    lw[i] = (unsigned int)l0 | ((unsigned int)l1 << 16);
  }
  size_t o = (size_t)grp * DH + lane * 8;
  *(uint4*)(s_hi + o) = make_uint4(hw[0], hw[1], hw[2], hw[3]);
  *(uint4*)(s_lo + o) = make_uint4(lw[0], lw[1], lw[2], lw[3]);
}

// ---------------- fused MFMA MLP with rolling weight prefetch ----------------
// 64 rows/block (wave w owns rows 16w..16w+15); 3-pass split-precision bf16 MFMA;
// z transposed through wave-private LDS slice -> no __syncthreads.
// Weights prefetched via 4-slot circular register buffer (lookahead 3); no lambdas.
__global__ __launch_bounds__(256, 3) void mlp_kernel(
    const ushort_t* __restrict__ s_hi, const ushort_t* __restrict__ s_lo,
    const ushort_t* __restrict__ w1p, const float* __restrict__ b1s,
    const ushort_t* __restrict__ w2p, const float* __restrict__ b2s,
    float* __restrict__ hout_f32, ushort_t* __restrict__ hout_bf16) {
  __shared__ float zt[64 * 66];  // [k_z 0..63][m 0..63 +pad2]
  const int tid = threadIdx.x;
  const int wave = tid >> 6;
  const int lane = tid & 63;
  const int quad = lane >> 4;
  const int l15 = lane & 15;
  const int m_base = wave * 16;
  const int row0 = blockIdx.x * 64;

  // ---- A-fragments (s rows, bf16 hi/lo) held in registers for the whole kernel ----
  int gr_ld = row0 + m_base + l15;
  if (gr_ld >= NN) gr_ld = NN - 1;  // clamp: stores are guarded
  frag_b16 a_hi[4], a_lo[4];
  #pragma unroll
  for (int tk = 0; tk < 4; ++tk) {
    size_t o = (size_t)gr_ld * DH + tk * 32 + quad * 8;
    FragU uh, ul;
    uh.u = *(const uint4*)(s_hi + o);
    ul.u = *(const uint4*)(s_lo + o);
    a_hi[tk] = uh.f;
    a_lo[tk] = ul.f;
  }

  frag_f32 hacc[8];
  #pragma unroll
  for (int tn = 0; tn < 8; ++tn) hacc[tn] = {0.f, 0.f, 0.f, 0.f};

  for (int ch = 0; ch < 8; ++ch) {
    // ---- stage A: z[64 rows][64-col chunk] = relu(s @ W1[:, ch*64..+64] + b1) ----
    frag_f32 za[4];
    #pragma unroll
    for (int tn = 0; tn < 4; ++tn) za[tn] = {0.f, 0.f, 0.f, 0.f};

    // flattened i = tk*4 + tn; tile = ch*16 + tn*4 + tk
    FragU wah[4], wal[4];
    #pragma unroll
    for (int i = 0; i < 3; ++i)
      ldw_rec(w1p, ch * 16 + (i & 3) * 4 + (i >> 2), lane, wah[i], wal[i]);
    #pragma unroll
    for (int i = 0; i < 16; ++i) {
      if (i + 3 < 16) {
        int ip = i + 3;
        ldw_rec(w1p, ch * 16 + (ip & 3) * 4 + (ip >> 2), lane, wah[ip & 3], wal[ip & 3]);
      }
      int tk = i >> 2, tn = i & 3, sl = i & 3;
      za[tn] = __builtin_amdgcn_mfma_f32_16x16x32_bf16(a_hi[tk], wah[sl].f, za[tn], 0, 0, 0);
      za[tn] = __builtin_amdgcn_mfma_f32_16x16x32_bf16(a_lo[tk], wah[sl].f, za[tn], 0, 0, 0);
      za[tn] = __builtin_amdgcn_mfma_f32_16x16x32_bf16(a_hi[tk], wal[sl].f, za[tn], 0, 0, 0);
    }

    // relu+bias, write to wave-private zt column slice (k rows = all, m cols = this wave's 16)
    #pragma unroll
    for (int tn = 0; tn < 4; ++tn) {
      float b1v = b1s[ch * 64 + tn * 16 + l15];
      float z0 = fmaxf(za[tn][0] + b1v, 0.f);
      float z1 = fmaxf(za[tn][1] + b1v, 0.f);
      float z2 = fmaxf(za[tn][2] + b1v, 0.f);
      float z3 = fmaxf(za[tn][3] + b1v, 0.f);
      float* zp = &zt[(tn * 16 + l15) * 66 + m_base + quad * 4];
      *(float2*)zp = make_float2(z0, z1);
      *(float2*)(zp + 2) = make_float2(z2, z3);
    }
    // no barrier: each wave reads back only its own m-slice

    // ---- stage B: hacc += z @ W2[ch*64..+64, :] ----
    #pragma unroll
    for (int kt = 0; kt < 2; ++kt) {
      FragU zh, zl;
      #pragma unroll
      for (int j = 0; j < 8; ++j) {
        int k = kt * 32 + quad * 8 + j;
        float v = zt[k * 66 + m_base + l15];
        split_bf16(v, zh.s[j], zl.s[j]);
      }
      int ktg = ch * 2 + kt;
      FragU wbh[4], wbl[4];
      #pragma unroll
      for (int i = 0; i < 3; ++i) ldw_rec(w2p, i * 16 + ktg, lane, wbh[i], wbl[i]);
      #pragma unroll
      for (int tn = 0; tn < 8; ++tn) {
        if (tn + 3 < 8)
          ldw_rec(w2p, (tn + 3) * 16 + ktg, lane, wbh[(tn + 3) & 3], wbl[(tn + 3) & 3]);
        int sl = tn & 3;
        hacc[tn] = __builtin_amdgcn_mfma_f32_16x16x32_bf16(zh.f, wbh[sl].f, hacc[tn], 0, 0, 0);
        hacc[tn] = __builtin_amdgcn_mfma_f32_16x16x32_bf16(zl.f, wbh[sl].f, hacc[tn], 0, 0, 0);
        hacc[tn] = __builtin_amdgcn_mfma_f32_16x16x32_bf16(zh.f, wbl[sl].f, hacc[tn], 0, 0, 0);
      }
    }
  }

  // ---- epilogue: h = relu(hacc + b2) -> fp32 and/or bf16 ----
  #pragma unroll
  for (int tn = 0; tn < 8; ++tn) {
    int col = tn * 16 + l15;
    float b2v = b2s[col];
    #pragma unroll
    for (int r = 0; r < 4; ++r) {
      int gr = row0 + m_base + quad * 4 + r;
      if (gr < NN) {
        float v = fmaxf(hacc[tn][r] + b2v, 0.f);
        if (hout_f32) hout_f32[(size_t)gr * DH + col] = v;
        if (hout_bf16) hout_bf16[(size_t)gr * DH + col] = rne_bf16(v);
      }
    }
  }
}

// ---------------- link predictor (fp32 VALU, reads final fp32 h) ----------------
__global__ __launch_bounds__(256) void predict_kernel(
    const float* __restrict__ h, const int* __restrict__ psrc, const int* __restrict__ pdst,
    const int* __restrict__ nsrc, const int* __restrict__ ndst,
    const float* __restrict__ Wp1, const float* __restrict__ bp1,
    const float* __restrict__ Wp2, const float* __restrict__ bp2,
    float* __restrict__ out) {
  __shared__ float g_tile[64 * 132];
  const int tid = threadIdx.x;
  const int s0 = blockIdx.x * 64;

  #pragma unroll
  for (int i = 0; i < 8; ++i) {
    int idx = tid + i * 256;
    int smp = s0 + (idx >> 5);
    int c4 = (idx & 31) << 2;
    float4 g = make_float4(0.f, 0.f, 0.f, 0.f);
    if (smp < 2 * PP) {
      int si = (smp < PP) ? psrc[smp] : nsrc[smp - PP];
      int di = (smp < PP) ? pdst[smp] : ndst[smp - PP];
      float4 a = *(const float4*)(h + (size_t)si * DH + c4);
      float4 b = *(const float4*)(h + (size_t)di * DH + c4);
      g = make_float4(a.x * b.x, a.y * b.y, a.z * b.z, a.w * b.w);
    }
    *(float4*)(&g_tile[(idx >> 5) * 132 + c4]) = g;
  }
  __syncthreads();

  const int tr = (tid >> 4) << 2;
  const int tc = (tid & 15) << 2;
  float z[4][4];
  #pragma unroll
  for (int r = 0; r < 4; ++r)
    #pragma unroll
    for (int c = 0; c < 4; ++c) z[r][c] = 0.f;

  for (int k = 0; k < DH; ++k) {
    float4 w = *(const float4*)(Wp1 + ((size_t)k << 6) + tc);
    float a[4];
    #pragma unroll
    for (int r = 0; r < 4; ++r) a[r] = g_tile[(tr + r) * 132 + k];
    #pragma unroll
    for (int r = 0; r < 4; ++r) {
      z[r][0] = fmaf(a[r], w.x, z[r][0]);
      z[r][1] = fmaf(a[r], w.y, z[r][1]);
      z[r][2] = fmaf(a[r], w.z, z[r][2]);
      z[r][3] = fmaf(a[r], w.w, z[r][3]);
    }
  }

  float4 b1v = *(const float4*)(bp1 + tc);
  float4 w2v = *(const float4*)(Wp2 + tc);
  float part[4];
  #pragma unroll
  for (int r = 0; r < 4; ++r) {
    part[r] = fmaxf(z[r][0] + b1v.x, 0.f) * w2v.x +
              fmaxf(z[r][1] + b1v.y, 0.f) * w2v.y +
              fmaxf(z[r][2] + b1v.z, 0.f) * w2v.z +
              fmaxf(z[r][3] + b1v.w, 0.f) * w2v.w;
  }
  #pragma unroll
  for (int off = 1; off < 16; off <<= 1) {
    #pragma unroll
    for (int r = 0; r < 4; ++r) part[r] += __shfl_xor(part[r], off, 64);
  }
  if ((tid & 15) == 0) {
    float bias = bp2[0];
    #pragma unroll
    for (int r = 0; r < 4; ++r) {
      int smp = s0 + tr + r;
      if (smp < 2 * PP) out[smp] = part[r] + bias;
    }
  }
}

// ---------------- launcher ----------------
extern "C" void kernel_launch(void* const* d_in, const int* in_sizes, int n_in,
                              void* d_out, int out_size, void* d_ws, size_t ws_size,
                              hipStream_t stream) {
  const float* x   = (const float*)d_in[0];
  const float* W1  = (const float*)d_in[1];
  const float* b1  = (const float*)d_in[2];
  const float* W2  = (const float*)d_in[3];
  const float* b2  = (const float*)d_in[4];
  const float* Wp1 = (const float*)d_in[5];
  const float* bp1 = (const float*)d_in[6];
  const float* Wp2 = (const float*)d_in[7];
  const float* bp2 = (const float*)d_in[8];
  const int* esrc = (const int*)d_in[9];
  const int* edst = (const int*)d_in[10];
  const int* psrc = (const int*)d_in[11];
  const int* pdst = (const int*)d_in[12];
  const int* nsrc = (const int*)d_in[13];
  const int* ndst = (const int*)d_in[14];

  float* out = (float*)d_out;
  float* out_pred = out;               // [2P]
  float* hbuf = out + 2 * (size_t)PP;  // [N,128] fp32 final h
  // intermediate bf16 h lives in the (dead until layer-2) hbuf region
  ushort_t* hbf = (ushort_t*)hbuf;     // [N,128] bf16 (25.6 MB of the 51.2 MB region)

  // ---- workspace layout (~59.5 MB) ----
  char* w = (char*)d_ws;
  ushort_t* s_hi = (ushort_t*)w;                        // N*128 bf16 = 25.6 MB
  ushort_t* s_lo = s_hi + (size_t)NN * DH;              // 25.6 MB
  ushort_t* w1p  = s_lo + (size_t)NN * DH;              // 3*128*64*16 ushorts = 768 KB
  ushort_t* w2p  = w1p + 3 * 128 * 64 * 16;             // 768 KB
  int* row_off = (int*)(w2p + 3 * 128 * 64 * 16);       // N+1
  int* csr     = row_off + (NN + 1);                    // E (6.4 MB)
  // CSR-build scratch aliases the (not-yet-written) s_hi region:
  int* deg    = (int*)w;
  int* inc    = deg + NN;
  int* bsum   = inc + NN;
  int* cursor = bsum + 256;

  // ---- CSR build ----
  hipMemsetAsync(deg, 0, NN * sizeof(int), stream);
  hist_kernel<<<(EE + 255) / 256, 256, 0, stream>>>(edst, deg);
  scan1_kernel<<<(NN + 511) / 512, 256, 0, stream>>>(deg, inc, bsum);
  scan2_kernel<<<1, 256, 0, stream>>>(bsum, (NN + 511) / 512);
  scan3_kernel<<<(NN + 255) / 256, 256, 0, stream>>>(inc, deg, bsum, row_off, cursor);
  scatter_kernel<<<(EE + 255) / 256, 256, 0, stream>>>(esrc, edst, cursor, csr);

  // ---- pack weights (bf16 hi/lo interleaved, MFMA fragment order) ----
  pack_w1_kernel<<<96, 256, 0, stream>>>(W1, w1p);
  pack_w2_kernel<<<96, 256, 0, stream>>>(W2, w2p);

  // ---- x -> bf16 for layer-0 gather ----
  cvt_bf16_kernel<<<(NN * DH / 4 + 255) / 256, 256, 0, stream>>>(x, hbf);

  // ---- 3 GIN layers: agg(hbf -> s planes), mlp(s -> hbf or hbuf) ----
  for (int l = 0; l < 3; ++l) {
    agg_kernel<<<(NN * 16 + 255) / 256, 256, 0, stream>>>(hbf, row_off, csr, s_hi, s_lo);
    mlp_kernel<<<(NN + 63) / 64, 256, 0, stream>>>(
        s_hi, s_lo,
        w1p + (size_t)l * 128 * 64 * 16, b1 + (size_t)l * DM,
        w2p + (size_t)l * 128 * 64 * 16, b2 + (size_t)l * DH,
        (l == 2) ? hbuf : nullptr, (l == 2) ? nullptr : hbf);
  }

  // ---- link prediction ----
  predict_kernel<<<(2 * PP + 63) / 64, 256, 0, stream>>>(
      hbuf, psrc, pdst, nsrc, ndst, Wp1, bp1, Wp2, bp2, out_pred);
}

// Round 7
// 924.374 us; speedup vs baseline: 2.3060x; 1.1749x over previous
//
#include <hip/hip_runtime.h>

typedef unsigned short ushort_t;

constexpr int NN = 100000;   // nodes
constexpr int EE = 1600000;  // edges
constexpr int PP = 100000;   // pos/neg samples
constexpr int DH = 128;
constexpr int DM = 512;

using frag_b16 = __attribute__((ext_vector_type(8))) short;   // 8 bf16 (4 VGPRs)
using frag_f32 = __attribute__((ext_vector_type(4))) float;   // 4 fp32 acc

union FragU {
  ushort_t s[8];
  uint4 u;
  frag_b16 f;
};

// split fp32 into bf16 hi (truncate) + bf16 lo (RNE of residual): x ~= hi+lo, err ~2^-17|x|
__device__ inline void split_bf16(float x, ushort_t& hi, ushort_t& lo) {
  unsigned int bx = __float_as_uint(x);
  hi = (ushort_t)(bx >> 16);
  float hf = __uint_as_float(bx & 0xFFFF0000u);
  float r = x - hf;
  unsigned int br = __float_as_uint(r);
  unsigned int rb = br + 0x7FFFu + ((br >> 16) & 1u);  // RNE
  lo = (ushort_t)(rb >> 16);
}

__device__ inline ushort_t rne_bf16(float x) {
  unsigned int u = __float_as_uint(x);
  unsigned int r = u + 0x7FFFu + ((u >> 16) & 1u);
  return (ushort_t)(r >> 16);
}

// unpack 2 bf16 from packed uint: low half -> a (even col), high half -> b (odd col)
__device__ inline void bf2x(unsigned int u, float& a, float& b) {
  a = __uint_as_float(u << 16);
  b = __uint_as_float(u & 0xFFFF0000u);
}

// load one 16B weight record (8 bf16, MFMA B-frag order)
__device__ inline void ldrec(const ushort_t* __restrict__ wp, int tile, int lane, FragU& f) {
  f.u = *(const uint4*)(wp + ((size_t)(tile * 64 + lane)) * 8);
}

// ---------------- CSR build (sort edges by dst, once per launch) ----------------

__global__ void hist_kernel(const int* __restrict__ dst, int* __restrict__ deg) {
  int i = blockIdx.x * 256 + threadIdx.x;
  if (i < EE) atomicAdd(&deg[dst[i]], 1);
}

__global__ void scan1_kernel(const int* __restrict__ deg, int* __restrict__ inc,
                             int* __restrict__ bsum) {
  __shared__ int buf[2][512];
  int base = blockIdx.x * 512;
  for (int i = threadIdx.x; i < 512; i += 256) {
    int g = base + i;
    buf[0][i] = (g < NN) ? deg[g] : 0;
  }
  __syncthreads();
  int cur = 0;
  for (int off = 1; off < 512; off <<= 1) {
    int nxt = cur ^ 1;
    for (int i = threadIdx.x; i < 512; i += 256) {
      int v = buf[cur][i];
      if (i >= off) v += buf[cur][i - off];
      buf[nxt][i] = v;
    }
    __syncthreads();
    cur = nxt;
  }
  for (int i = threadIdx.x; i < 512; i += 256) {
    int g = base + i;
    if (g < NN) inc[g] = buf[cur][i];
  }
  if (threadIdx.x == 0) bsum[blockIdx.x] = buf[cur][511];
}

__global__ void scan2_kernel(int* __restrict__ bsum, int nb) {
  __shared__ int buf[2][256];
  int i = threadIdx.x;
  buf[0][i] = (i < nb) ? bsum[i] : 0;
  __syncthreads();
  int cur = 0;
  for (int off = 1; off < 256; off <<= 1) {
    int nxt = cur ^ 1;
    int v = buf[cur][i];
    if (i >= off) v += buf[cur][i - off];
    buf[nxt][i] = v;
    __syncthreads();
    cur = nxt;
  }
  if (i < nb) bsum[i] = (i == 0) ? 0 : buf[cur][i - 1];
}

__global__ void scan3_kernel(const int* __restrict__ inc, const int* __restrict__ deg,
                             const int* __restrict__ bsum,
                             int* __restrict__ row_off, int* __restrict__ cursor) {
  int i = blockIdx.x * 256 + threadIdx.x;
  if (i < NN) {
    int excl = inc[i] - deg[i] + bsum[i >> 9];
    row_off[i] = excl;
    cursor[i] = excl;
    if (i == NN - 1) row_off[NN] = excl + deg[i];
  }
}

__global__ void scatter_kernel(const int* __restrict__ esrc, const int* __restrict__ edst,
                               int* __restrict__ cursor, int* __restrict__ csr) {
  int i = blockIdx.x * 256 + threadIdx.x;
  if (i < EE) {
    int d = edst[i];
    int p = atomicAdd(&cursor[d], 1);
    csr[p] = esrc[i];
  }
}

// ---------------- weight packing: MFMA B-frag order, 16B records, RNE bf16 ----------
// record r = tile_global*64+lane holds 8 bf16 at wp + r*8 (ushorts).
// W1 [L][128(K)][512(N)]: tile = tn*4+tk (tn<32,tk<4), n=tn*16+(lane&15), k=tk*32+(lane>>4)*8+j
__global__ void pack_w1_kernel(const float* __restrict__ W1, ushort_t* __restrict__ wp) {
  int t = blockIdx.x * 256 + threadIdx.x;
  if (t >= 3 * 128 * 64) return;
  int lane = t & 63;
  int tile = t >> 6;
  int tk = tile & 3;
  int tn = (tile >> 2) & 31;
  int layer = tile >> 7;
  int n = tn * 16 + (lane & 15);
  int k0 = tk * 32 + (lane >> 4) * 8;
  const float* src = W1 + (size_t)layer * DH * DM;
  size_t dst = (size_t)t * 8;
  #pragma unroll
  for (int j = 0; j < 8; ++j) wp[dst + j] = rne_bf16(src[(size_t)(k0 + j) * DM + n]);
}

// W2 [L][512(K)][128(N)]: tile = tn*16+tk (tn<8, tk<16)
__global__ void pack_w2_kernel(const float* __restrict__ W2, ushort_t* __restrict__ wp) {
  int t = blockIdx.x * 256 + threadIdx.x;
  if (t >= 3 * 128 * 64) return;
  int lane = t & 63;
  int tile = t >> 6;
  int tk = tile & 15;
  int tn = (tile >> 4) & 7;
  int layer = tile >> 7;
  int n = tn * 16 + (lane & 15);
  int k0 = tk * 32 + (lane >> 4) * 8;
  const float* src = W2 + (size_t)layer * DM * DH;
  size_t dst = (size_t)t * 8;
  #pragma unroll
  for (int j = 0; j < 8; ++j) wp[dst + j] = rne_bf16(src[(size_t)(k0 + j) * DH + n]);
}

// ---------------- x -> bf16 convert (layer-0 gather source) ----------------
__global__ void cvt_bf16_kernel(const float* __restrict__ x, ushort_t* __restrict__ xb) {
  int i = blockIdx.x * 256 + threadIdx.x;  // n = NN*DH/4 quads
  if (i < NN * DH / 4) {
    float4 v = ((const float4*)x)[i];
    ushort4 o;
    o.x = rne_bf16(v.x); o.y = rne_bf16(v.y); o.z = rne_bf16(v.z); o.w = rne_bf16(v.w);
    ((ushort4*)xb)[i] = o;
  }
}

// ---------------- aggregation: s[dst] = h[dst] + sum h[src] over bf16 h ----------------
// 16 lanes/row, 16 B (8 bf16 cols) per lane; 16 rows per 256-thread block.
__global__ __launch_bounds__(256) void agg_kernel(const ushort_t* __restrict__ hbf,
                                                  const int* __restrict__ row_off,
                                                  const int* __restrict__ csr,
                                                  ushort_t* __restrict__ s_hi,
                                                  ushort_t* __restrict__ s_lo) {
  int t = blockIdx.x * 256 + threadIdx.x;
  int grp = t >> 4;
  int lane = t & 15;
  if (grp >= NN) return;
  const uint4* hp = (const uint4*)hbf;  // 16 uint4 per 128-col row
  float acc[8];
  {
    uint4 v = hp[(size_t)grp * 16 + lane];
    bf2x(v.x, acc[0], acc[1]);
    bf2x(v.y, acc[2], acc[3]);
    bf2x(v.z, acc[4], acc[5]);
    bf2x(v.w, acc[6], acc[7]);
  }
  int e = row_off[grp];
  int e1 = row_off[grp + 1];
  for (; e + 1 < e1; e += 2) {  // two gathers in flight
    uint4 a = hp[(size_t)csr[e] * 16 + lane];
    uint4 b = hp[(size_t)csr[e + 1] * 16 + lane];
    float f0, f1;
    bf2x(a.x, f0, f1); acc[0] += f0; acc[1] += f1;
    bf2x(a.y, f0, f1); acc[2] += f0; acc[3] += f1;
    bf2x(a.z, f0, f1); acc[4] += f0; acc[5] += f1;
    bf2x(a.w, f0, f1); acc[6] += f0; acc[7] += f1;
    bf2x(b.x, f0, f1); acc[0] += f0; acc[1] += f1;
    bf2x(b.y, f0, f1); acc[2] += f0; acc[3] += f1;
    bf2x(b.z, f0, f1); acc[4] += f0; acc[5] += f1;
    bf2x(b.w, f0, f1); acc[6] += f0; acc[7] += f1;
  }
  if (e < e1) {
    uint4 a = hp[(size_t)csr[e] * 16 + lane];
    float f0, f1;
    bf2x(a.x, f0, f1); acc[0] += f0; acc[1] += f1;
    bf2x(a.y, f0, f1); acc[2] += f0; acc[3] += f1;
    bf2x(a.z, f0, f1); acc[4] += f0; acc[5] += f1;
    bf2x(a.w, f0, f1); acc[6] += f0; acc[7] += f1;
  }
  // split to hi/lo planes, 16 B per lane each
  unsigned int hw[4], lw[4];
  #pragma unroll
  for (int i = 0; i < 4; ++i) {
    ushort_t h0, l0, h1, l1;
    split_bf16(acc[2 * i], h0, l0);
    split_bf16(acc[2 * i + 1], h1, l1);
    hw[i] = (unsigned int)h0 | ((unsigned int)h1 << 16);
    lw[i] = (unsigned int)l0 | ((unsigned int)l1 << 16);
  }
  size_t o = (size_t)grp * DH + lane * 8;
  *(uint4*)(s_hi + o) = make_uint4(hw[0], hw[1], hw[2], hw[3]);
  *(uint4*)(s_lo + o) = make_uint4(lw[0], lw[1], lw[2], lw[3]);
}

// ---------------- fused MFMA MLP, 32 rows/wave (2 m-tiles), 2-pass split ----------
// Block = 128 threads (2 waves), 64 rows. Wave w owns rows 32w..32w+31.
// Passes: a_hi*b + a_lo*b (weights single RNE bf16). z through wave-private LDS
// slice -> no __syncthreads. Weight records batched 4-8 in flight for ILP.
__global__ __launch_bounds__(128) void mlp_kernel(
    const ushort_t* __restrict__ s_hi, const ushort_t* __restrict__ s_lo,
    const ushort_t* __restrict__ w1p, const float* __restrict__ b1s,
    const ushort_t* __restrict__ w2p, const float* __restrict__ b2s,
    float* __restrict__ hout_f32, ushort_t* __restrict__ hout_bf16) {
  __shared__ float zt[64 * 66];  // [k_z 0..63][m 0..63 +pad2]
  const int tid = threadIdx.x;
  const int wave = tid >> 6;      // 0..1
  const int lane = tid & 63;
  const int quad = lane >> 4;
  const int l15 = lane & 15;
  const int m_base = wave * 32;
  const int row0 = blockIdx.x * 64;

  // ---- A-fragments: 2 m-tiles x 4 k-tiles, bf16 hi/lo, in registers all kernel ----
  frag_b16 a_hi[2][4], a_lo[2][4];
  #pragma unroll
  for (int ms = 0; ms < 2; ++ms) {
    int gr = row0 + m_base + ms * 16 + l15;
    if (gr >= NN) gr = NN - 1;  // clamp: stores are guarded
    #pragma unroll
    for (int tk = 0; tk < 4; ++tk) {
      size_t o = (size_t)gr * DH + tk * 32 + quad * 8;
      FragU uh, ul;
      uh.u = *(const uint4*)(s_hi + o);
      ul.u = *(const uint4*)(s_lo + o);
      a_hi[ms][tk] = uh.f;
      a_lo[ms][tk] = ul.f;
    }
  }

  frag_f32 hacc[2][8];
  #pragma unroll
  for (int ms = 0; ms < 2; ++ms)
    #pragma unroll
    for (int tn = 0; tn < 8; ++tn) hacc[ms][tn] = {0.f, 0.f, 0.f, 0.f};

  for (int ch = 0; ch < 8; ++ch) {
    // ---- stage A: z[64 rows][64-col chunk] = relu(s @ W1[:, ch*64..+64] + b1) ----
    frag_f32 za[2][4];
    #pragma unroll
    for (int ms = 0; ms < 2; ++ms)
      #pragma unroll
      for (int tn = 0; tn < 4; ++tn) za[ms][tn] = {0.f, 0.f, 0.f, 0.f};

    FragU wb[2][4];
    #pragma unroll
    for (int tn = 0; tn < 4; ++tn) ldrec(w1p, ch * 16 + tn * 4, lane, wb[0][tn]);
    #pragma unroll
    for (int tk = 0; tk < 4; ++tk) {
      int cur = tk & 1, nxt = cur ^ 1;
      if (tk < 3) {
        #pragma unroll
        for (int tn = 0; tn < 4; ++tn)
          ldrec(w1p, ch * 16 + tn * 4 + tk + 1, lane, wb[nxt][tn]);
      }
      #pragma unroll
      for (int tn = 0; tn < 4; ++tn) {
        #pragma unroll
        for (int ms = 0; ms < 2; ++ms) {
          za[ms][tn] = __builtin_amdgcn_mfma_f32_16x16x32_bf16(a_hi[ms][tk], wb[cur][tn].f,
                                                               za[ms][tn], 0, 0, 0);
          za[ms][tn] = __builtin_amdgcn_mfma_f32_16x16x32_bf16(a_lo[ms][tk], wb[cur][tn].f,
                                                               za[ms][tn], 0, 0, 0);
        }
      }
    }

    // relu+bias, write wave-private zt slice (all 64 k-cols, this wave's 32 m)
    #pragma unroll
    for (int tn = 0; tn < 4; ++tn) {
      float b1v = b1s[ch * 64 + tn * 16 + l15];
      #pragma unroll
      for (int ms = 0; ms < 2; ++ms) {
        float z0 = fmaxf(za[ms][tn][0] + b1v, 0.f);
        float z1 = fmaxf(za[ms][tn][1] + b1v, 0.f);
        float z2 = fmaxf(za[ms][tn][2] + b1v, 0.f);
        float z3 = fmaxf(za[ms][tn][3] + b1v, 0.f);
        float* zp = &zt[(tn * 16 + l15) * 66 + m_base + ms * 16 + quad * 4];
        *(float2*)zp = make_float2(z0, z1);
        *(float2*)(zp + 2) = make_float2(z2, z3);
      }
    }
    // no barrier: each wave reads back only its own m-slice (lgkmcnt ordering)

    // ---- stage B: hacc += z @ W2[ch*64..+64, :] ----
    #pragma unroll
    for (int kt = 0; kt < 2; ++kt) {
      int ktg = ch * 2 + kt;
      FragU wb2[8];
      #pragma unroll
      for (int tn = 0; tn < 8; ++tn) ldrec(w2p, tn * 16 + ktg, lane, wb2[tn]);
      FragU zh[2], zl[2];
      #pragma unroll
      for (int ms = 0; ms < 2; ++ms) {
        #pragma unroll
        for (int j = 0; j < 8; ++j) {
          int k = kt * 32 + quad * 8 + j;
          float v = zt[k * 66 + m_base + ms * 16 + l15];
          split_bf16(v, zh[ms].s[j], zl[ms].s[j]);
        }
      }
      #pragma unroll
      for (int tn = 0; tn < 8; ++tn) {
        #pragma unroll
        for (int ms = 0; ms < 2; ++ms) {
          hacc[ms][tn] = __builtin_amdgcn_mfma_f32_16x16x32_bf16(zh[ms].f, wb2[tn].f,
                                                                 hacc[ms][tn], 0, 0, 0);
          hacc[ms][tn] = __builtin_amdgcn_mfma_f32_16x16x32_bf16(zl[ms].f, wb2[tn].f,
                                                                 hacc[ms][tn], 0, 0, 0);
        }
      }
    }
  }

  // ---- epilogue: h = relu(hacc + b2) -> fp32 and/or bf16 ----
  #pragma unroll
  for (int tn = 0; tn < 8; ++tn) {
    int col = tn * 16 + l15;
    float b2v = b2s[col];
    #pragma unroll
    for (int ms = 0; ms < 2; ++ms) {
      #pragma unroll
      for (int r = 0; r < 4; ++r) {
        int gr = row0 + m_base + ms * 16 + quad * 4 + r;
        if (gr < NN) {
          float v = fmaxf(hacc[ms][tn][r] + b2v, 0.f);
          if (hout_f32) hout_f32[(size_t)gr * DH + col] = v;
          if (hout_bf16) hout_bf16[(size_t)gr * DH + col] = rne_bf16(v);
        }
      }
    }
  }
}

// ---------------- link predictor (fp32 VALU, reads final fp32 h) ----------------
__global__ __launch_bounds__(256) void predict_kernel(
    const float* __restrict__ h, const int* __restrict__ psrc, const int* __restrict__ pdst,
    const int* __restrict__ nsrc, const int* __restrict__ ndst,
    const float* __restrict__ Wp1, const float* __restrict__ bp1,
    const float* __restrict__ Wp2, const float* __restrict__ bp2,
    float* __restrict__ out) {
  __shared__ float g_tile[64 * 132];
  const int tid = threadIdx.x;
  const int s0 = blockIdx.x * 64;

  #pragma unroll
  for (int i = 0; i < 8; ++i) {
    int idx = tid + i * 256;
    int smp = s0 + (idx >> 5);
    int c4 = (idx & 31) << 2;
    float4 g = make_float4(0.f, 0.f, 0.f, 0.f);
    if (smp < 2 * PP) {
      int si = (smp < PP) ? psrc[smp] : nsrc[smp - PP];
      int di = (smp < PP) ? pdst[smp] : ndst[smp - PP];
      float4 a = *(const float4*)(h + (size_t)si * DH + c4);
      float4 b = *(const float4*)(h + (size_t)di * DH + c4);
      g = make_float4(a.x * b.x, a.y * b.y, a.z * b.z, a.w * b.w);
    }
    *(float4*)(&g_tile[(idx >> 5) * 132 + c4]) = g;
  }
  __syncthreads();

  const int tr = (tid >> 4) << 2;
  const int tc = (tid & 15) << 2;
  float z[4][4];
  #pragma unroll
  for (int r = 0; r < 4; ++r)
    #pragma unroll
    for (int c = 0; c < 4; ++c) z[r][c] = 0.f;

  for (int k = 0; k < DH; ++k) {
    float4 w = *(const float4*)(Wp1 + ((size_t)k << 6) + tc);
    float a[4];
    #pragma unroll
    for (int r = 0; r < 4; ++r) a[r] = g_tile[(tr + r) * 132 + k];
    #pragma unroll
    for (int r = 0; r < 4; ++r) {
      z[r][0] = fmaf(a[r], w.x, z[r][0]);
      z[r][1] = fmaf(a[r], w.y, z[r][1]);
      z[r][2] = fmaf(a[r], w.z, z[r][2]);
      z[r][3] = fmaf(a[r], w.w, z[r][3]);
    }
  }

  float4 b1v = *(const float4*)(bp1 + tc);
  float4 w2v = *(const float4*)(Wp2 + tc);
  float part[4];
  #pragma unroll
  for (int r = 0; r < 4; ++r) {
    part[r] = fmaxf(z[r][0] + b1v.x, 0.f) * w2v.x +
              fmaxf(z[r][1] + b1v.y, 0.f) * w2v.y +
              fmaxf(z[r][2] + b1v.z, 0.f) * w2v.z +
              fmaxf(z[r][3] + b1v.w, 0.f) * w2v.w;
  }
  #pragma unroll
  for (int off = 1; off < 16; off <<= 1) {
    #pragma unroll
    for (int r = 0; r < 4; ++r) part[r] += __shfl_xor(part[r], off, 64);
  }
  if ((tid & 15) == 0) {
    float bias = bp2[0];
    #pragma unroll
    for (int r = 0; r < 4; ++r) {
      int smp = s0 + tr + r;
      if (smp < 2 * PP) out[smp] = part[r] + bias;
    }
  }
}

// ---------------- launcher ----------------
extern "C" void kernel_launch(void* const* d_in, const int* in_sizes, int n_in,
                              void* d_out, int out_size, void* d_ws, size_t ws_size,
                              hipStream_t stream) {
  const float* x   = (const float*)d_in[0];
  const float* W1  = (const float*)d_in[1];
  const float* b1  = (const float*)d_in[2];
  const float* W2  = (const float*)d_in[3];
  const float* b2  = (const float*)d_in[4];
  const float* Wp1 = (const float*)d_in[5];
  const float* bp1 = (const float*)d_in[6];
  const float* Wp2 = (const float*)d_in[7];
  const float* bp2 = (const float*)d_in[8];
  const int* esrc = (const int*)d_in[9];
  const int* edst = (const int*)d_in[10];
  const int* psrc = (const int*)d_in[11];
  const int* pdst = (const int*)d_in[12];
  const int* nsrc = (const int*)d_in[13];
  const int* ndst = (const int*)d_in[14];

  float* out = (float*)d_out;
  float* out_pred = out;               // [2P]
  float* hbuf = out + 2 * (size_t)PP;  // [N,128] fp32 final h
  // intermediate bf16 h lives in the (dead until layer-2) hbuf region
  ushort_t* hbf = (ushort_t*)hbuf;     // [N,128] bf16 (25.6 MB of the 51.2 MB region)

  // ---- workspace layout (~58.7 MB) ----
  char* w = (char*)d_ws;
  ushort_t* s_hi = (ushort_t*)w;                        // N*128 bf16 = 25.6 MB
  ushort_t* s_lo = s_hi + (size_t)NN * DH;              // 25.6 MB
  ushort_t* w1p  = s_lo + (size_t)NN * DH;              // 3*128*64*8 ushorts = 393 KB
  ushort_t* w2p  = w1p + 3 * 128 * 64 * 8;              // 393 KB
  int* row_off = (int*)(w2p + 3 * 128 * 64 * 8);        // N+1
  int* csr     = row_off + (NN + 1);                    // E (6.4 MB)
  // CSR-build scratch aliases the (not-yet-written) s_hi region:
  int* deg    = (int*)w;
  int* inc    = deg + NN;
  int* bsum   = inc + NN;
  int* cursor = bsum + 256;

  // ---- CSR build ----
  hipMemsetAsync(deg, 0, NN * sizeof(int), stream);
  hist_kernel<<<(EE + 255) / 256, 256, 0, stream>>>(edst, deg);
  scan1_kernel<<<(NN + 511) / 512, 256, 0, stream>>>(deg, inc, bsum);
  scan2_kernel<<<1, 256, 0, stream>>>(bsum, (NN + 511) / 512);
  scan3_kernel<<<(NN + 255) / 256, 256, 0, stream>>>(inc, deg, bsum, row_off, cursor);
  scatter_kernel<<<(EE + 255) / 256, 256, 0, stream>>>(esrc, edst, cursor, csr);

  // ---- pack weights (RNE bf16, MFMA fragment order, 16B records) ----
  pack_w1_kernel<<<96, 256, 0, stream>>>(W1, w1p);
  pack_w2_kernel<<<96, 256, 0, stream>>>(W2, w2p);

  // ---- x -> bf16 for layer-0 gather ----
  cvt_bf16_kernel<<<(NN * DH / 4 + 255) / 256, 256, 0, stream>>>(x, hbf);

  // ---- 3 GIN layers: agg(hbf -> s planes), mlp(s -> hbf or hbuf) ----
  for (int l = 0; l < 3; ++l) {
    agg_kernel<<<(NN * 16 + 255) / 256, 256, 0, stream>>>(hbf, row_off, csr, s_hi, s_lo);
    mlp_kernel<<<(NN + 63) / 64, 128, 0, stream>>>(
        s_hi, s_lo,
        w1p + (size_t)l * 128 * 64 * 8, b1 + (size_t)l * DM,
        w2p + (size_t)l * 128 * 64 * 8, b2 + (size_t)l * DH,
        (l == 2) ? hbuf : nullptr, (l == 2) ? nullptr : hbf);
  }

  // ---- link prediction ----
  predict_kernel<<<(2 * PP + 63) / 64, 256, 0, stream>>>(
      hbuf, psrc, pdst, nsrc, ndst, Wp1, bp1, Wp2, bp2, out_pred);
}